// Round 1
// baseline (298.450 us; speedup 1.0000x reference)
//
#include <hip/hip_runtime.h>
#include <hip/hip_bf16.h>
#include <stdint.h>

// DynamicFc: out = (tiny per-sample MLP with generated weights) + residuals.
// B=8192, F_DIM=1024, LOW=128, MID=32, params-dim J=8192 (p1: j=l*32+m, p2: j=4096+m*128+l)
//
// Pipeline (all bf16 MFMA 16x16x32, fp32 accum):
//  K0: convert weights to bf16 in ws
//  K1: f_low = f@Wf^T+bf (fp32, layout [l][b]);  pf_low = pf@Wpf^T+bpf (bf16 [b][k]);
//      rsum = bf16(f+pf) [b][n]
//  K2 mode0: h_part[g][m][b] = sum_{l in group g} f_low[b,l]*(pg_w1[j]·pf_low[b] + pg_b1[j])
//  K2 mode1: g[b][l] = sum_m relu(h)[b,m]*(pg_w2[j]·pf_low[b] + pg_b2[j])   (h reduced+relu'd in staging)
//  K3: out = g@W2^T + b2 + rsum

#define BATCH 8192

typedef __attribute__((ext_vector_type(8))) short bf16x8;
typedef __attribute__((ext_vector_type(4))) float f32x4;

__device__ __forceinline__ ushort f2bf(float x) {
    union { float f; uint32_t u; } v; v.f = x;
    uint32_t r = (v.u + 0x7FFFu + ((v.u >> 16) & 1u)) >> 16;
    return (ushort)r;
}
__device__ __forceinline__ ushort4 f2bf4(float4 v) {
    ushort4 o; o.x = f2bf(v.x); o.y = f2bf(v.y); o.z = f2bf(v.z); o.w = f2bf(v.w); return o;
}

// ---------------- K0: weight conversion (fp32 -> bf16) ----------------
// virtual float4-index space: pg_w 262144 | wf 32768 | wpf 32768 | w2 32768  => 360448 = 1408*256
__global__ __launch_bounds__(256) void k0_convert(
    const float* __restrict__ pgw, const float* __restrict__ wf,
    const float* __restrict__ wpf, const float* __restrict__ w2,
    ushort* __restrict__ o_pg, ushort* __restrict__ o_wf,
    ushort* __restrict__ o_wpf, ushort* __restrict__ o_w2)
{
    int i = blockIdx.x * 256 + threadIdx.x;
    const float* src; ushort* dst; int off;
    if (i < 262144)      { src = pgw; dst = o_pg;  off = i; }
    else if (i < 294912) { src = wf;  dst = o_wf;  off = i - 262144; }
    else if (i < 327680) { src = wpf; dst = o_wpf; off = i - 294912; }
    else                 { src = w2;  dst = o_w2;  off = i - 327680; }
    float4 v = ((const float4*)src)[off];
    ((ushort4*)dst)[off] = f2bf4(v);
}

// ---------------- K1: input projections + residual sum ----------------
// grid 256, block 256 (4 waves). M-tile = 32 rows. waves 0,1: f-GEMM rows 0-15/16-31; waves 2,3: pf-GEMM.
__global__ __launch_bounds__(256) void k1_proj(
    const float* __restrict__ f, const float* __restrict__ pf,
    const ushort* __restrict__ wf_bf, const ushort* __restrict__ wpf_bf,
    const float* __restrict__ bf_bias, const float* __restrict__ bpf_bias,
    ushort* __restrict__ rsum, float* __restrict__ f_lowT, ushort* __restrict__ pf_low)
{
    __shared__ ushort Af[32 * 136];   // padded stride 136 bf16 = 272B (breaks b128 bank conflicts)
    __shared__ ushort Apf[32 * 136];
    const int tid = threadIdx.x;
    const int lane = tid & 63, wid = tid >> 6;
    const int q = lane >> 4, r15 = lane & 15;
    const int b0 = blockIdx.x * 32;
    const int srow = tid >> 3;      // 0..31
    const int skc  = tid & 7;       // 16-elem k chunk

    f32x4 c[8];
#pragma unroll
    for (int i = 0; i < 8; i++) c[i] = (f32x4){0.f, 0.f, 0.f, 0.f};

    float4 fa[4], pa[4];
    const float* fbase  = f  + (size_t)(b0 + srow) * 1024 + skc * 16;
    const float* pbase  = pf + (size_t)(b0 + srow) * 1024 + skc * 16;
#pragma unroll
    for (int i = 0; i < 4; i++) { fa[i] = ((const float4*)fbase)[i]; pa[i] = ((const float4*)pbase)[i]; }

    const ushort* Alds = (wid < 2) ? Af : Apf;
    const ushort* W    = (wid < 2) ? wf_bf : wpf_bf;
    const int rowbase  = (wid & 1) * 16;

    for (int r8 = 0; r8 < 8; r8++) {
        const int kr = r8 * 128;
        __syncthreads();
        // cvt + stage + rsum
        ushort* arow = Af  + srow * 136 + skc * 16;
        ushort* prow = Apf + srow * 136 + skc * 16;
        ushort* rrow = rsum + (size_t)(b0 + srow) * 1024 + kr + skc * 16;
#pragma unroll
        for (int i = 0; i < 4; i++) {
            ((ushort4*)arow)[i] = f2bf4(fa[i]);
            ((ushort4*)prow)[i] = f2bf4(pa[i]);
            float4 s; s.x = fa[i].x + pa[i].x; s.y = fa[i].y + pa[i].y;
            s.z = fa[i].z + pa[i].z; s.w = fa[i].w + pa[i].w;
            ((ushort4*)rrow)[i] = f2bf4(s);
        }
        __syncthreads();
        if (r8 < 7) {
            const float* fn = fbase + (kr + 128);
            const float* pn = pbase + (kr + 128);
#pragma unroll
            for (int i = 0; i < 4; i++) { fa[i] = ((const float4*)fn)[i]; pa[i] = ((const float4*)pn)[i]; }
        }
        // compute
        bf16x8 af[4];
#pragma unroll
        for (int ks = 0; ks < 4; ks++)
            af[ks] = *(const bf16x8*)(Alds + (rowbase + r15) * 136 + ks * 32 + q * 8);
#pragma unroll
        for (int cg = 0; cg < 8; cg++) {
            const ushort* wp = W + (size_t)(cg * 16 + r15) * 1024 + kr + q * 8;
#pragma unroll
            for (int ks = 0; ks < 4; ks++) {
                bf16x8 bfr = *(const bf16x8*)(wp + ks * 32);
                c[cg] = __builtin_amdgcn_mfma_f32_16x16x32_bf16(af[ks], bfr, c[cg], 0, 0, 0);
            }
        }
    }
    // epilogue: C rows = samples (b = b0+rowbase+q*4+r), cols = l (cg*16+r15)
    if (wid < 2) {
#pragma unroll
        for (int cg = 0; cg < 8; cg++) {
            int l = cg * 16 + r15;
            float bias = bf_bias[l];
#pragma unroll
            for (int r = 0; r < 4; r++) {
                int b = b0 + rowbase + q * 4 + r;
                f_lowT[(size_t)l * 8192 + b] = c[cg][r] + bias;
            }
        }
    } else {
#pragma unroll
        for (int cg = 0; cg < 8; cg++) {
            int l = cg * 16 + r15;
            float bias = bpf_bias[l];
#pragma unroll
            for (int r = 0; r < 4; r++) {
                int b = b0 + rowbase + q * 4 + r;
                pf_low[(size_t)b * 128 + l] = f2bf(c[cg][r] + bias);
            }
        }
    }
}

// ---------------- K2: fused dynamic-weight GEMM + contraction ----------------
// grid 512 (= 128 sample-blocks of 64 x 4 groups), block 256 (4 waves x 16 samples).
// mode 0: rows j = grp*1024 + slice*32 + row    (slice = l-local, row = m), scale = f_low[b,l],  out h_part
// mode 1: rows j = 4096 + grp*32 + slice*128 + row (slice = m, row = l-local), scale = relu(h)[b,m], out g
__global__ __launch_bounds__(256) void k2_dyn(
    const ushort* __restrict__ pgw_bf, const ushort* __restrict__ pf_low,
    const float* __restrict__ pg_b, const float* __restrict__ f_lowT,
    const float* __restrict__ h_in, float* __restrict__ out_hpart,
    float* __restrict__ out_g, int mode)
{
    __shared__ ushort Asl[4 * 32 * 136];     // 4 slices of [32 rows][128+8 k] bf16
    __shared__ float scale_lds[32 * 64];     // [slice][b_local]
    const int tid = threadIdx.x;
    const int lane = tid & 63, wid = tid >> 6;
    const int q = lane >> 4, r15 = lane & 15;
    const int sb = blockIdx.x >> 2, grp = blockIdx.x & 3;
    const int b0 = sb * 64;
    const int rowBase   = mode ? (4096 + grp * 32) : (grp * 1024);
    const int rowStride = mode ? 128 : 32;
    const int srow = tid >> 3, skc = tid & 7;

    // stage scale_lds
    {
        int ll = tid >> 3, bc = tid & 7;
        int b = b0 + bc * 8;
        float4 s0, s1;
        if (mode == 0) {
            const float* src = f_lowT + (size_t)(grp * 32 + ll) * 8192 + b;
            s0 = ((const float4*)src)[0]; s1 = ((const float4*)src)[1];
        } else {
            s0 = (float4){0, 0, 0, 0}; s1 = (float4){0, 0, 0, 0};
#pragma unroll
            for (int g = 0; g < 4; g++) {
                const float* src = h_in + (size_t)g * 262144 + (size_t)ll * 8192 + b;
                float4 a = ((const float4*)src)[0], e = ((const float4*)src)[1];
                s0.x += a.x; s0.y += a.y; s0.z += a.z; s0.w += a.w;
                s1.x += e.x; s1.y += e.y; s1.z += e.z; s1.w += e.w;
            }
            s0.x = fmaxf(s0.x, 0.f); s0.y = fmaxf(s0.y, 0.f); s0.z = fmaxf(s0.z, 0.f); s0.w = fmaxf(s0.w, 0.f);
            s1.x = fmaxf(s1.x, 0.f); s1.y = fmaxf(s1.y, 0.f); s1.z = fmaxf(s1.z, 0.f); s1.w = fmaxf(s1.w, 0.f);
        }
        ((float4*)(scale_lds + ll * 64 + bc * 8))[0] = s0;
        ((float4*)(scale_lds + ll * 64 + bc * 8))[1] = s1;
    }

    // B-fragments: pf_low for this wave's 16 samples, resident across whole kernel
    const int bw = b0 + wid * 16;
    bf16x8 bfr[4];
#pragma unroll
    for (int ks = 0; ks < 4; ks++)
        bfr[ks] = *(const bf16x8*)(pf_low + (size_t)(bw + r15) * 128 + ks * 32 + q * 8);

    f32x4 acc[2];
    acc[0] = (f32x4){0.f, 0.f, 0.f, 0.f};
    acc[1] = (f32x4){0.f, 0.f, 0.f, 0.f};

    uint4 st[8];
#pragma unroll
    for (int sl = 0; sl < 4; sl++) {
        const ushort* src = pgw_bf + (size_t)(rowBase + sl * rowStride + srow) * 128 + skc * 16;
        st[sl * 2 + 0] = ((const uint4*)src)[0];
        st[sl * 2 + 1] = ((const uint4*)src)[1];
    }

    for (int rnd = 0; rnd < 8; rnd++) {
        __syncthreads();
#pragma unroll
        for (int sl = 0; sl < 4; sl++) {
            uint4* d = (uint4*)(Asl + sl * 4352 + srow * 136 + skc * 16);
            d[0] = st[sl * 2 + 0]; d[1] = st[sl * 2 + 1];
        }
        __syncthreads();
        if (rnd < 7) {
#pragma unroll
            for (int sl = 0; sl < 4; sl++) {
                int slice = (rnd + 1) * 4 + sl;
                const ushort* src = pgw_bf + (size_t)(rowBase + slice * rowStride + srow) * 128 + skc * 16;
                st[sl * 2 + 0] = ((const uint4*)src)[0];
                st[sl * 2 + 1] = ((const uint4*)src)[1];
            }
        }
#pragma unroll
        for (int sl = 0; sl < 4; sl++) {
            const int slice = rnd * 4 + sl;
            const float s = scale_lds[slice * 64 + wid * 16 + r15];
            const ushort* ab = Asl + sl * 4352 + r15 * 136 + q * 8;
            const float* biasp = pg_b + rowBase + slice * rowStride + q * 4;
#pragma unroll
            for (int half = 0; half < 2; half++) {
                f32x4 cc = (f32x4){0.f, 0.f, 0.f, 0.f};
                const ushort* ah = ab + half * 2176;
#pragma unroll
                for (int ks = 0; ks < 4; ks++)
                    cc = __builtin_amdgcn_mfma_f32_16x16x32_bf16(*(const bf16x8*)(ah + ks * 32), bfr[ks], cc, 0, 0, 0);
                float4 bias = *(const float4*)(biasp + half * 16);
                acc[half][0] += s * (cc[0] + bias.x);
                acc[half][1] += s * (cc[1] + bias.y);
                acc[half][2] += s * (cc[2] + bias.z);
                acc[half][3] += s * (cc[3] + bias.w);
            }
        }
    }
    // epilogue: C rows = j-local (half*16+q*4+r), cols = b (bw+r15)
    if (mode == 0) {
        float* dst = out_hpart + (size_t)grp * 262144;
#pragma unroll
        for (int half = 0; half < 2; half++)
#pragma unroll
            for (int r = 0; r < 4; r++)
                dst[(size_t)(half * 16 + q * 4 + r) * 8192 + bw + r15] = acc[half][r];
    } else {
#pragma unroll
        for (int half = 0; half < 2; half++)
#pragma unroll
            for (int r = 0; r < 4; r++)
                out_g[(size_t)(bw + r15) * 128 + grp * 32 + half * 16 + q * 4 + r] = acc[half][r];
    }
}

// ---------------- K3: final projection + bias + residual ----------------
// grid 2048 (128 m-blocks x 16 n-blocks), block 256 (4 waves). tile M=64, N=64.
__global__ __launch_bounds__(256) void k3_out(
    const float* __restrict__ g, const ushort* __restrict__ w2_bf,
    const float* __restrict__ b2, const ushort* __restrict__ rsum,
    float* __restrict__ out)
{
    __shared__ ushort Ag[64 * 136];
    __shared__ ushort Bw[64 * 136];
    const int tid = threadIdx.x;
    const int lane = tid & 63, wid = tid >> 6;
    const int q = lane >> 4, r15 = lane & 15;
    const int mb = blockIdx.x >> 4, nb = blockIdx.x & 15;
    const int b0 = mb * 64, n0 = nb * 64;
    {
        int row = tid >> 2, kc = tid & 3;     // 64 rows x 4 chunks of 32
        const float4* gp = (const float4*)(g + (size_t)(b0 + row) * 128 + kc * 32);
        ushort* ad = Ag + row * 136 + kc * 32;
#pragma unroll
        for (int i = 0; i < 8; i++) ((ushort4*)ad)[i] = f2bf4(gp[i]);
        const uint4* wp = (const uint4*)(w2_bf + (size_t)(n0 + row) * 128 + kc * 32);
        uint4* bd = (uint4*)(Bw + row * 136 + kc * 32);
#pragma unroll
        for (int i = 0; i < 4; i++) bd[i] = wp[i];
    }
    __syncthreads();
    const int rw = wid * 16;
    bf16x8 af[4];
#pragma unroll
    for (int ks = 0; ks < 4; ks++)
        af[ks] = *(const bf16x8*)(Ag + (rw + r15) * 136 + ks * 32 + q * 8);
    f32x4 c[4];
#pragma unroll
    for (int i = 0; i < 4; i++) c[i] = (f32x4){0.f, 0.f, 0.f, 0.f};
#pragma unroll
    for (int cg = 0; cg < 4; cg++) {
        const ushort* bp = Bw + (cg * 16 + r15) * 136 + q * 8;
#pragma unroll
        for (int ks = 0; ks < 4; ks++)
            c[cg] = __builtin_amdgcn_mfma_f32_16x16x32_bf16(af[ks], *(const bf16x8*)(bp + ks * 32), c[cg], 0, 0, 0);
    }
#pragma unroll
    for (int cg = 0; cg < 4; cg++) {
        int n = n0 + cg * 16 + r15;
        float bias = b2[n];
#pragma unroll
        for (int r = 0; r < 4; r++) {
            int b = b0 + rw + q * 4 + r;
            float rs = __uint_as_float((uint32_t)rsum[(size_t)b * 1024 + n] << 16);
            out[(size_t)b * 1024 + n] = c[cg][r] + bias + rs;
        }
    }
}

// ---------------- launch ----------------
extern "C" void kernel_launch(void* const* d_in, const int* in_sizes, int n_in,
                              void* d_out, int out_size, void* d_ws, size_t ws_size,
                              hipStream_t stream)
{
    const float* f    = (const float*)d_in[0];
    const float* pf   = (const float*)d_in[1];
    const float* wf   = (const float*)d_in[2];
    const float* bfb  = (const float*)d_in[3];
    const float* wpf  = (const float*)d_in[4];
    const float* bpfb = (const float*)d_in[5];
    const float* w2   = (const float*)d_in[6];
    const float* b2   = (const float*)d_in[7];
    const float* pgw  = (const float*)d_in[8];
    const float* pgb  = (const float*)d_in[9];

    char* ws = (char*)d_ws;
    ushort* pgw_bf = (ushort*)(ws + 0);          // 2 MB
    ushort* wf_bf  = (ushort*)(ws + 2097152);    // 256 KB
    ushort* wpf_bf = (ushort*)(ws + 2359296);    // 256 KB
    ushort* w2_bf  = (ushort*)(ws + 2621440);    // 256 KB
    ushort* rsum   = (ushort*)(ws + 2883584);    // 16 MB
    ushort* pf_low = (ushort*)(ws + 19660800);   // 2 MB
    float*  f_lowT = (float*)(ws + 21757952);    // 4 MB
    float*  h_part = (float*)(ws + 25952256);    // 4 MB (4 groups x 32 x 8192 f32)
    float*  g_ws   = (float*)(ws + 30146560);    // 4 MB
    float*  out    = (float*)d_out;

    k0_convert<<<dim3(1408), dim3(256), 0, stream>>>(pgw, wf, wpf, w2, pgw_bf, wf_bf, wpf_bf, w2_bf);
    k1_proj<<<dim3(256), dim3(256), 0, stream>>>(f, pf, wf_bf, wpf_bf, bfb, bpfb, rsum, f_lowT, pf_low);
    k2_dyn<<<dim3(512), dim3(256), 0, stream>>>(pgw_bf, pf_low, pgb, f_lowT, h_part, h_part, g_ws, 0);
    k2_dyn<<<dim3(512), dim3(256), 0, stream>>>(pgw_bf, pf_low, pgb, f_lowT, h_part, h_part, g_ws, 1);
    k3_out<<<dim3(2048), dim3(256), 0, stream>>>(g_ws, w2_bf, b2, rsum, out);
}